// Round 2
// baseline (867.120 us; speedup 1.0000x reference)
//
#include <hip/hip_runtime.h>

#define TPB   256
#define TT    28          // t-windows per chunk
#define SEG   155         // TT*5 + 15 positions per chunk segment
#define NF    32
#define T_TOT 406
#define LLEN  2048
#define NPAIR 496
#define FSW   36          // padded feature stride (multiple of 4 for b128 align)

// load one chunk's segment into fs buffer: feature-major transpose + XOR swizzle
__device__ __forceinline__ void stage_seg(const float* __restrict__ xb,
                                          float* __restrict__ fsb,
                                          int chunk, int tid) {
    const int l0 = chunk * TT * 5;
    #pragma unroll
    for (int it = 0; it < 5; ++it) {
        int i   = tid + it * TPB;        // 0..1279
        int f   = i / 40;
        int q   = i - f * 40;
        int pos = q * 4;
        float v[4] = {0.f, 0.f, 0.f, 0.f};
        int lg = l0 + pos;
        if (pos + 3 < SEG && lg + 3 < LLEN) {
            float4 t4 = *(const float4*)&xb[f * LLEN + lg];   // 16B aligned: l0*4=chunk*560
            v[0] = t4.x; v[1] = t4.y; v[2] = t4.z; v[3] = t4.w;
        } else {
            #pragma unroll
            for (int d = 0; d < 4; ++d)
                if (pos + d < SEG && lg + d < LLEN) v[d] = xb[f * LLEN + lg + d];
        }
        #pragma unroll
        for (int d = 0; d < 4; ++d) {
            int p2 = pos + d;
            if (p2 < SEG) {
                int sw = ((p2 ^ (p2 >> 3)) & 7) << 2;
                fsb[p2 * FSW + (f ^ sw)] = v[d];
            }
        }
    }
}

__global__ __launch_bounds__(TPB, 2)
void tscorr_kernel(const float* __restrict__ x, float* __restrict__ out) {
    __shared__ float  fs[2][SEG * FSW];   // 44640 B double-buffered segment
    __shared__ float2 st[NF * TT];        //  7168 B (mu, norm) per (f, tloc)

    const int tid = threadIdx.x;
    const int g   = blockIdx.x;           // 0: chunks 0..7, 1: chunks 8..14
    const int b   = blockIdx.y;
    const int c_lo = g ? 8 : 0;
    const int c_hi = g ? 15 : 8;
    const float* xb = x + (size_t)b * NF * LLEN;
    float* ob       = out + (size_t)b * NPAIR * T_TOT;

    // compute-thread mapping: pair-block (bi,bj) x t-quad
    const int pb = tid / 7;
    const int tl = tid - pb * 7;
    int bi = 0, bj = 0;
    {
        int rem = (pb < 36) ? pb : 0;
        while (rem >= 8 - bi) { rem -= 8 - bi; ++bi; }
        bj = bi + rem;
    }
    const bool active = (tid < 252);
    const bool diag   = active && (bi == bj);
    const int  t0loc  = tl * 4;

    stage_seg(xb, fs[0], c_lo, tid);
    int cur = 0;

    for (int chunk = c_lo; chunk < c_hi; ++chunk) {
        __syncthreads();                               // fs[cur] ready; st from prev chunk consumed
        if (chunk + 1 < c_hi) stage_seg(xb, fs[cur ^ 1], chunk + 1, tid);

        float A[4][4][4];
        float S[4][4];
        if (active) {
            #pragma unroll
            for (int t = 0; t < 4; ++t)
                #pragma unroll
                for (int r = 0; r < 4; ++r) {
                    S[t][r] = 0.f;
                    #pragma unroll
                    for (int c = 0; c < 4; ++c) A[t][r][c] = 0.f;
                }

            const float* fsb = fs[cur];
            const int lbase = t0loc * 5;
            #pragma unroll
            for (int u = 0; u < 7; ++u) {
                float q[4][4];
                float cs[4];
                #pragma unroll
                for (int r = 0; r < 4; ++r) {
                    cs[r] = 0.f;
                    #pragma unroll
                    for (int c = 0; c < 4; ++c) q[r][c] = 0.f;
                }
                #pragma unroll
                for (int d = 0; d < 5; ++d) {
                    int l  = lbase + u * 5 + d;
                    int sw = ((l ^ (l >> 3)) & 7) << 2;
                    const float4 vi = *(const float4*)&fsb[l * FSW + ((bi * 4) ^ sw)];
                    const float4 vj = *(const float4*)&fsb[l * FSW + ((bj * 4) ^ sw)];
                    float xi[4] = {vi.x, vi.y, vi.z, vi.w};
                    float xj[4] = {vj.x, vj.y, vj.z, vj.w};
                    #pragma unroll
                    for (int r = 0; r < 4; ++r)
                        #pragma unroll
                        for (int c = 0; c < 4; ++c)
                            q[r][c] = fmaf(xi[r], xj[c], q[r][c]);
                    if (diag) {
                        #pragma unroll
                        for (int r = 0; r < 4; ++r) cs[r] += xi[r];
                    }
                }
                #pragma unroll
                for (int t = 0; t < 4; ++t) {
                    if (u >= t && u <= t + 3) {        // compile-time after unroll
                        #pragma unroll
                        for (int r = 0; r < 4; ++r) {
                            #pragma unroll
                            for (int c = 0; c < 4; ++c) A[t][r][c] += q[r][c];
                            if (diag) S[t][r] += cs[r];
                        }
                    }
                }
            }

            if (diag) {                                 // publish mu, n = sqrt(Gff - 20 mu^2)
                #pragma unroll
                for (int r = 0; r < 4; ++r)
                    #pragma unroll
                    for (int t = 0; t < 4; ++t) {
                        float mu = S[t][r] * 0.05f;
                        float n2 = A[t][r][r] - 20.f * mu * mu;
                        st[(bi * 4 + r) * TT + t0loc + t] =
                            make_float2(mu, sqrtf(fmaxf(n2, 0.f)));
                    }
            }
        }
        __syncthreads();                               // st visible

        if (active) {
            float2 si[4][4], sj[4][4];                 // [row][t]
            #pragma unroll
            for (int r = 0; r < 4; ++r) {
                const float2* pi = &st[(bi * 4 + r) * TT + t0loc];
                const float2* pj = &st[(bj * 4 + r) * TT + t0loc];
                #pragma unroll
                for (int t = 0; t < 4; ++t) { si[r][t] = pi[t]; sj[r][t] = pj[t]; }
            }
            const int tg    = chunk * TT + t0loc;       // global t of quad start
            const int nvalid = T_TOT - tg;              // always even
            #pragma unroll
            for (int r = 0; r < 4; ++r) {
                int fi = bi * 4 + r;
                #pragma unroll
                for (int c = 0; c < 4; ++c) {
                    int fj = bj * 4 + c;
                    if (fj > fi) {
                        int p = fi * (63 - fi) / 2 + (fj - fi - 1);
                        float* po = ob + (size_t)p * T_TOT + tg;
                        float v[4];
                        #pragma unroll
                        for (int t = 0; t < 4; ++t) {
                            float num = A[t][r][c] - 20.f * si[r][t].x * sj[c][t].x;
                            float den = si[r][t].y * sj[c][t].y + 1e-8f;
                            v[t] = num * __builtin_amdgcn_rcpf(den);
                        }
                        if (nvalid >= 2) *(float2*)&po[0] = make_float2(v[0], v[1]); // 8B aligned
                        if (nvalid >= 4) *(float2*)&po[2] = make_float2(v[2], v[3]);
                    }
                }
            }
        }
        cur ^= 1;
    }
}

extern "C" void kernel_launch(void* const* d_in, const int* in_sizes, int n_in,
                              void* d_out, int out_size, void* d_ws, size_t ws_size,
                              hipStream_t stream) {
    const float* x = (const float*)d_in[0];
    float* out     = (float*)d_out;
    dim3 grid(2, 256);          // 2 chunk-groups x 256 batches, each owns contiguous rows in time
    hipLaunchKernelGGL(tscorr_kernel, grid, dim3(TPB), 0, stream, x, out);
}

// Round 3
// 536.978 us; speedup vs baseline: 1.6148x; 1.6148x over previous
//
#include <hip/hip_runtime.h>

#define TPB     256
#define TT      28          // t-windows per chunk
#define SEG     155         // TT*5 + 15 segment positions
#define NF      32
#define T_TOT   406
#define LLEN    2048
#define NPAIR   496
#define FSW     36          // padded feature stride (multiple of 4 for b128 align)
#define NCHUNK  15
#define SLAB    (NPAIR * TT)    // 13888 bf16 elems per (b,chunk) slab
#define SLAB_U4 (SLAB / 8)      // 1736 uint4 per slab
#define RPB     16              // output rows per expand-block

__device__ __forceinline__ unsigned short f2bf(float f) {
    unsigned int u = __float_as_uint(f);
    u += 0x7fffu + ((u >> 16) & 1u);           // RNE
    return (unsigned short)(u >> 16);
}

// ---------------------------------------------------------------------------
// Kernel 1: compute correlations for one (b, chunk) tile, dump bf16 slab to ws
// (phases A..C2 identical to the validated 518us kernel)
// ---------------------------------------------------------------------------
__global__ __launch_bounds__(TPB, 2)
void tscorr_slab(const float* __restrict__ x, unsigned short* __restrict__ ws,
                 int b_off) {
    __shared__ float          fs[SEG * FSW];
    __shared__ float2         st[NF * TT];
    __shared__ alignas(16) unsigned short ot[SLAB];

    const int tid   = threadIdx.x;
    const int chunk = blockIdx.x;
    const int bloc  = blockIdx.y;
    const int b     = b_off + bloc;
    const int t0    = chunk * TT;
    const int l0    = t0 * 5;
    const float* xb = x + (size_t)b * NF * LLEN;

    // Phase A: load segment, transpose + XOR swizzle
    for (int idx = tid; idx < NF * SEG; idx += TPB) {
        int f   = idx / SEG;
        int pos = idx - f * SEG;
        int lg  = l0 + pos;
        float v = (lg < LLEN) ? xb[f * LLEN + lg] : 0.0f;
        int sw  = ((pos ^ (pos >> 3)) & 7) << 2;
        fs[pos * FSW + (f ^ sw)] = v;
    }
    __syncthreads();

    int pb = 0, tl = 0, bi = 0, bj = 0, t0loc = 0;
    float A[4][4][4];
    const bool active = (tid < 252);
    if (active) {
        pb = tid / 7;
        tl = tid - pb * 7;
        int rem = pb;
        while (rem >= 8 - bi) { rem -= 8 - bi; ++bi; }
        bj = bi + rem;
        t0loc = tl * 4;

        // Phase C1: chunk-Gram accumulation
        #pragma unroll
        for (int t = 0; t < 4; ++t)
            #pragma unroll
            for (int r = 0; r < 4; ++r)
                #pragma unroll
                for (int c = 0; c < 4; ++c) A[t][r][c] = 0.f;

        float S[4][4];
        const bool diag = (bi == bj);
        #pragma unroll
        for (int t = 0; t < 4; ++t)
            #pragma unroll
            for (int r = 0; r < 4; ++r) S[t][r] = 0.f;

        const int lbase = t0loc * 5;
        #pragma unroll
        for (int u = 0; u < 7; ++u) {
            float q[4][4];
            float cs[4];
            #pragma unroll
            for (int r = 0; r < 4; ++r) {
                cs[r] = 0.f;
                #pragma unroll
                for (int c = 0; c < 4; ++c) q[r][c] = 0.f;
            }
            #pragma unroll
            for (int d = 0; d < 5; ++d) {
                int l  = lbase + u * 5 + d;
                int sw = ((l ^ (l >> 3)) & 7) << 2;
                const float4 vi = *(const float4*)&fs[l * FSW + ((bi * 4) ^ sw)];
                const float4 vj = *(const float4*)&fs[l * FSW + ((bj * 4) ^ sw)];
                float xi[4] = {vi.x, vi.y, vi.z, vi.w};
                float xj[4] = {vj.x, vj.y, vj.z, vj.w};
                #pragma unroll
                for (int r = 0; r < 4; ++r)
                    #pragma unroll
                    for (int c = 0; c < 4; ++c)
                        q[r][c] = fmaf(xi[r], xj[c], q[r][c]);
                if (diag) {
                    #pragma unroll
                    for (int r = 0; r < 4; ++r) cs[r] += xi[r];
                }
            }
            #pragma unroll
            for (int t = 0; t < 4; ++t) {
                if (u >= t && u <= t + 3) {
                    #pragma unroll
                    for (int r = 0; r < 4; ++r) {
                        #pragma unroll
                        for (int c = 0; c < 4; ++c) A[t][r][c] += q[r][c];
                        if (diag) S[t][r] += cs[r];
                    }
                }
            }
        }

        if (diag) {
            #pragma unroll
            for (int r = 0; r < 4; ++r)
                #pragma unroll
                for (int t = 0; t < 4; ++t) {
                    float mu = S[t][r] * 0.05f;
                    float n2 = A[t][r][r] - 20.f * mu * mu;
                    st[(bi * 4 + r) * TT + t0loc + t] =
                        make_float2(mu, sqrtf(fmaxf(n2, 0.f)));
                }
        }
    }
    __syncthreads();

    // Phase C2: correction + bf16 staging into LDS tile
    if (active) {
        float2 si[4][4], sj[4][4];
        #pragma unroll
        for (int r = 0; r < 4; ++r) {
            const float2* pi = &st[(bi * 4 + r) * TT + t0loc];
            const float2* pj = &st[(bj * 4 + r) * TT + t0loc];
            #pragma unroll
            for (int t = 0; t < 4; ++t) { si[r][t] = pi[t]; sj[r][t] = pj[t]; }
        }
        #pragma unroll
        for (int r = 0; r < 4; ++r) {
            int fi = bi * 4 + r;
            #pragma unroll
            for (int c = 0; c < 4; ++c) {
                int fj = bj * 4 + c;
                if (fj > fi) {
                    int p = fi * (63 - fi) / 2 + (fj - fi - 1);
                    unsigned short bf[4];
                    #pragma unroll
                    for (int t = 0; t < 4; ++t) {
                        float num = A[t][r][c] - 20.f * si[r][t].x * sj[c][t].x;
                        float den = si[r][t].y * sj[c][t].y + 1e-8f;
                        bf[t] = f2bf(num * __builtin_amdgcn_rcpf(den));
                    }
                    uint2 w;
                    w.x = (unsigned)bf[0] | ((unsigned)bf[1] << 16);
                    w.y = (unsigned)bf[2] | ((unsigned)bf[3] << 16);
                    *(uint2*)&ot[p * TT + t0loc] = w;   // 8B aligned
                }
            }
        }
    }
    __syncthreads();

    // Phase D: lane-contiguous slab dump (full lines, written once)
    {
        const uint4* src = (const uint4*)ot;
        uint4* dst = (uint4*)(ws + ((size_t)bloc * NCHUNK + chunk) * SLAB);
        for (int i = tid; i < SLAB_U4; i += TPB) dst[i] = src[i];
    }
}

// ---------------------------------------------------------------------------
// Kernel 2: layout transform ws[b][c][p][28] bf16 -> out[b][p][406] f32
// ---------------------------------------------------------------------------
__global__ __launch_bounds__(256)
void tscorr_expand(const unsigned short* __restrict__ ws,
                   float* __restrict__ out, int b_off) {
    __shared__ float buf[RPB][408];
    const int tid = threadIdx.x;
    const int pg  = blockIdx.x;           // 0..30, rows [pg*16, pg*16+16)
    const int blo = blockIdx.y;
    const int b   = b_off + blo;
    const uint4* wsu = (const uint4*)ws;

    // gather: 15 chunks x 16 rows x 28 t  (each chunk strip = 896B contiguous)
    for (int idx = tid; idx < NCHUNK * 56; idx += 256) {
        int c = idx / 56;
        int w = idx - c * 56;
        uint4 v = wsu[((size_t)blo * NCHUNK + c) * SLAB_U4 + (size_t)pg * 56 + w];
        unsigned int h[8] = { v.x & 0xffffu, v.x >> 16, v.y & 0xffffu, v.y >> 16,
                              v.z & 0xffffu, v.z >> 16, v.w & 0xffffu, v.w >> 16 };
        int g = w * 8;
        #pragma unroll
        for (int e = 0; e < 8; ++e) {
            int ge    = g + e;
            int p_off = ge / 28;
            int t28   = ge - p_off * 28;
            int t     = c * TT + t28;
            if (t < T_TOT) buf[p_off][t] = __uint_as_float(h[e] << 16);
        }
    }
    __syncthreads();

    // scatter: 16 full rows = 25984B contiguous, lane-contiguous float2 sweep
    float* ob = out + ((size_t)b * NPAIR + (size_t)pg * RPB) * T_TOT;
    for (int idx = tid; idx < RPB * (T_TOT / 2); idx += 256) {
        int rr = idx / (T_TOT / 2);
        int tw = idx - rr * (T_TOT / 2);
        *(float2*)&ob[(size_t)rr * T_TOT + tw * 2] =
            *(const float2*)&buf[rr][tw * 2];
    }
}

// ---------------------------------------------------------------------------
// Fallback (ws too small): validated direct kernel (round-1, 518us)
// ---------------------------------------------------------------------------
__global__ __launch_bounds__(TPB, 2)
void tscorr_direct(const float* __restrict__ x, float* __restrict__ out) {
    __shared__ float          fs[SEG * FSW];
    __shared__ float2         st[NF * TT];
    __shared__ unsigned short ot[NPAIR * TT];

    const int tid   = threadIdx.x;
    const int chunk = blockIdx.x;
    const int b     = blockIdx.y;
    const int t0    = chunk * TT;
    const int l0    = t0 * 5;
    const float* xb = x + (size_t)b * NF * LLEN;

    for (int idx = tid; idx < NF * SEG; idx += TPB) {
        int f   = idx / SEG;
        int pos = idx - f * SEG;
        int lg  = l0 + pos;
        float v = (lg < LLEN) ? xb[f * LLEN + lg] : 0.0f;
        int sw  = ((pos ^ (pos >> 3)) & 7) << 2;
        fs[pos * FSW + (f ^ sw)] = v;
    }
    __syncthreads();

    int pb = 0, tl = 0, bi = 0, bj = 0, t0loc = 0;
    float A[4][4][4];
    const bool active = (tid < 252);
    if (active) {
        pb = tid / 7;
        tl = tid - pb * 7;
        int rem = pb;
        while (rem >= 8 - bi) { rem -= 8 - bi; ++bi; }
        bj = bi + rem;
        t0loc = tl * 4;

        #pragma unroll
        for (int t = 0; t < 4; ++t)
            #pragma unroll
            for (int r = 0; r < 4; ++r)
                #pragma unroll
                for (int c = 0; c < 4; ++c) A[t][r][c] = 0.f;

        float S[4][4];
        const bool diag = (bi == bj);
        #pragma unroll
        for (int t = 0; t < 4; ++t)
            #pragma unroll
            for (int r = 0; r < 4; ++r) S[t][r] = 0.f;

        const int lbase = t0loc * 5;
        #pragma unroll
        for (int u = 0; u < 7; ++u) {
            float q[4][4];
            float cs[4];
            #pragma unroll
            for (int r = 0; r < 4; ++r) {
                cs[r] = 0.f;
                #pragma unroll
                for (int c = 0; c < 4; ++c) q[r][c] = 0.f;
            }
            #pragma unroll
            for (int d = 0; d < 5; ++d) {
                int l  = lbase + u * 5 + d;
                int sw = ((l ^ (l >> 3)) & 7) << 2;
                const float4 vi = *(const float4*)&fs[l * FSW + ((bi * 4) ^ sw)];
                const float4 vj = *(const float4*)&fs[l * FSW + ((bj * 4) ^ sw)];
                float xi[4] = {vi.x, vi.y, vi.z, vi.w};
                float xj[4] = {vj.x, vj.y, vj.z, vj.w};
                #pragma unroll
                for (int r = 0; r < 4; ++r)
                    #pragma unroll
                    for (int c = 0; c < 4; ++c)
                        q[r][c] = fmaf(xi[r], xj[c], q[r][c]);
                if (diag) {
                    #pragma unroll
                    for (int r = 0; r < 4; ++r) cs[r] += xi[r];
                }
            }
            #pragma unroll
            for (int t = 0; t < 4; ++t) {
                if (u >= t && u <= t + 3) {
                    #pragma unroll
                    for (int r = 0; r < 4; ++r) {
                        #pragma unroll
                        for (int c = 0; c < 4; ++c) A[t][r][c] += q[r][c];
                        if (diag) S[t][r] += cs[r];
                    }
                }
            }
        }

        if (diag) {
            #pragma unroll
            for (int r = 0; r < 4; ++r)
                #pragma unroll
                for (int t = 0; t < 4; ++t) {
                    float mu = S[t][r] * 0.05f;
                    float n2 = A[t][r][r] - 20.f * mu * mu;
                    st[(bi * 4 + r) * TT + t0loc + t] =
                        make_float2(mu, sqrtf(fmaxf(n2, 0.f)));
                }
        }
    }
    __syncthreads();

    if (active) {
        float2 si[4][4], sj[4][4];
        #pragma unroll
        for (int r = 0; r < 4; ++r) {
            const float2* pi = &st[(bi * 4 + r) * TT + t0loc];
            const float2* pj = &st[(bj * 4 + r) * TT + t0loc];
            #pragma unroll
            for (int t = 0; t < 4; ++t) { si[r][t] = pi[t]; sj[r][t] = pj[t]; }
        }
        const int nvalid = T_TOT - (t0 + t0loc);
        const bool all4  = (nvalid >= 4);
        #pragma unroll
        for (int r = 0; r < 4; ++r) {
            int fi = bi * 4 + r;
            #pragma unroll
            for (int c = 0; c < 4; ++c) {
                int fj = bj * 4 + c;
                if (fj > fi) {
                    int p = fi * (63 - fi) / 2 + (fj - fi - 1);
                    unsigned short bf[4];
                    #pragma unroll
                    for (int t = 0; t < 4; ++t) {
                        float num = A[t][r][c] - 20.f * si[r][t].x * sj[c][t].x;
                        float den = si[r][t].y * sj[c][t].y + 1e-8f;
                        bf[t] = f2bf(num * __builtin_amdgcn_rcpf(den));
                    }
                    if (all4) {
                        uint2 w;
                        w.x = (unsigned)bf[0] | ((unsigned)bf[1] << 16);
                        w.y = (unsigned)bf[2] | ((unsigned)bf[3] << 16);
                        *(uint2*)&ot[p * TT + t0loc] = w;
                    } else {
                        #pragma unroll
                        for (int t = 0; t < 4; ++t)
                            if (t < nvalid) ot[p * TT + t0loc + t] = bf[t];
                    }
                }
            }
        }
    }
    __syncthreads();

    for (int k = tid; k < NPAIR * (TT / 2); k += TPB) {
        int p  = k / (TT / 2);
        int tp = k - p * (TT / 2);
        int t  = t0 + tp * 2;
        if (t < T_TOT) {
            unsigned int v = *(const unsigned int*)&ot[p * TT + tp * 2];
            float2 o;
            o.x = __uint_as_float((v & 0xffffu) << 16);
            o.y = __uint_as_float(v & 0xffff0000u);
            *(float2*)&out[((size_t)b * NPAIR + p) * T_TOT + t] = o;
        }
    }
}

extern "C" void kernel_launch(void* const* d_in, const int* in_sizes, int n_in,
                              void* d_out, int out_size, void* d_ws, size_t ws_size,
                              hipStream_t stream) {
    (void)in_sizes; (void)n_in; (void)out_size;
    const float* x = (const float*)d_in[0];
    float* out     = (float*)d_out;

    const size_t per_b = (size_t)NCHUNK * SLAB * sizeof(unsigned short); // 416640 B
    int nb_fit = (ws_size >= per_b) ? (int)(ws_size / per_b) : 0;

    if (nb_fit < 1) {
        // workspace too small: validated direct path
        hipLaunchKernelGGL(tscorr_direct, dim3(NCHUNK, 256), dim3(TPB), 0, stream,
                           x, out);
        return;
    }

    int nb = nb_fit > 256 ? 256 : nb_fit;
    unsigned short* ws = (unsigned short*)d_ws;
    for (int b0 = 0; b0 < 256; b0 += nb) {
        int n = (256 - b0 < nb) ? (256 - b0) : nb;
        hipLaunchKernelGGL(tscorr_slab, dim3(NCHUNK, n), dim3(TPB), 0, stream,
                           x, ws, b0);
        hipLaunchKernelGGL(tscorr_expand, dim3(NPAIR / RPB, n), dim3(256), 0, stream,
                           ws, out, b0);
    }
}

// Round 4
// 381.654 us; speedup vs baseline: 2.2720x; 1.4070x over previous
//
#include <hip/hip_runtime.h>

#define TPB    256
#define TT     28          // t-windows per block
#define SEG    155         // TT*5 + 15 segment positions
#define NF     32
#define T_TOT  406
#define LLEN   2048
#define NPAIR  496
#define STSTR  29          // st row stride (float2) — breaks bank alignment

// fs layout: row l (0..154), 32 floats = 8 float4-groups, group slot XOR-swizzled:
//   word(l, f) = l*32 + ((g ^ (l & 7)) << 2) + e   where g = f>>2, e = f&3
// Row stride 128B = bank-aligned; per-row XOR spreads each column-group across
// the 8 slots as l varies. C1 reads are same-l across lanes -> conflict-free.

__global__ __launch_bounds__(TPB, 4)
void tscorr_kernel(const float* __restrict__ x, float* __restrict__ out) {
    __shared__ float  fs[SEG * 32];       // 19840 B
    __shared__ float2 st[NF * STSTR];     //  7424 B  (mu, norm)

    const int tid   = threadIdx.x;
    const int chunk = blockIdx.x;
    const int b     = blockIdx.y;
    const int t0    = chunk * TT;
    const int l0    = t0 * 5;             // multiple of 4 (140*chunk)
    const float* xb = x + (size_t)b * NF * LLEN;
    float* ob       = out + (size_t)b * NPAIR * T_TOT;

    // ---------------- Phase A: coalesced float4 load + 4-way-swizzled LDS write
    {
        const int f  = tid >> 3;          // 0..31
        const int p4 = tid & 7;           // 0..7
        const int g  = f >> 2, e = f & 3;
        #pragma unroll
        for (int it = 0; it < 5; ++it) {
            int pos = it * 32 + p4 * 4;   // 0..156
            int lg  = l0 + pos;
            float v[4] = {0.f, 0.f, 0.f, 0.f};
            if (lg + 3 < LLEN) {
                float4 t4 = *(const float4*)&xb[f * LLEN + lg];   // 16B aligned
                v[0] = t4.x; v[1] = t4.y; v[2] = t4.z; v[3] = t4.w;
            } else {
                #pragma unroll
                for (int k = 0; k < 4; ++k)
                    if (lg + k < LLEN) v[k] = xb[f * LLEN + lg + k];
            }
            #pragma unroll
            for (int k = 0; k < 4; ++k) {
                int row = pos + k;
                if (row < SEG)
                    fs[row * 32 + (((g ^ (row & 7)) << 2) | e)] = v[k];
            }
        }
    }
    __syncthreads();

    // compute-thread mapping: lanes share the same t-quad (tl), pair-block varies
    const int tl = tid / 36;              // 0..6 (t-quad)
    const int pb = tid - tl * 36;         // 0..35 (upper-tri 4x4 block incl. diag)
    const bool active = (tid < 252);
    int bi = 0, bj = 0;
    {
        int rem = active ? pb : 0;
        while (rem >= 8 - bi) { rem -= 8 - bi; ++bi; }
        bj = bi + rem;
    }
    const bool diag  = active && (bi == bj);
    const int  t0loc = tl * 4;

    float A[4][4][4];
    float S[4][4];
    if (active) {
        #pragma unroll
        for (int t = 0; t < 4; ++t)
            #pragma unroll
            for (int r = 0; r < 4; ++r) {
                S[t][r] = 0.f;
                #pragma unroll
                for (int c = 0; c < 4; ++c) A[t][r][c] = 0.f;
            }

        const int lbase = t0loc * 5;      // tl*20
        #pragma unroll
        for (int u = 0; u < 7; ++u) {
            float q[4][4];
            float cs[4];
            #pragma unroll
            for (int r = 0; r < 4; ++r) {
                cs[r] = 0.f;
                #pragma unroll
                for (int c = 0; c < 4; ++c) q[r][c] = 0.f;
            }
            #pragma unroll
            for (int d = 0; d < 5; ++d) {
                int l    = lbase + u * 5 + d;
                int base = l * 32;
                int sw   = (l & 7);
                const float4 vi = *(const float4*)&fs[base + ((bi ^ sw) << 2)];
                const float4 vj = *(const float4*)&fs[base + ((bj ^ sw) << 2)];
                float xi[4] = {vi.x, vi.y, vi.z, vi.w};
                float xj[4] = {vj.x, vj.y, vj.z, vj.w};
                #pragma unroll
                for (int r = 0; r < 4; ++r)
                    #pragma unroll
                    for (int c = 0; c < 4; ++c)
                        q[r][c] = fmaf(xi[r], xj[c], q[r][c]);
                if (diag) {
                    #pragma unroll
                    for (int r = 0; r < 4; ++r) cs[r] += xi[r];
                }
            }
            #pragma unroll
            for (int t = 0; t < 4; ++t) {
                if (u >= t && u <= t + 3) {           // compile-time after unroll
                    #pragma unroll
                    for (int r = 0; r < 4; ++r) {
                        #pragma unroll
                        for (int c = 0; c < 4; ++c) A[t][r][c] += q[r][c];
                        if (diag) S[t][r] += cs[r];
                    }
                }
            }
        }

        if (diag) {                                   // publish mu, n
            #pragma unroll
            for (int r = 0; r < 4; ++r)
                #pragma unroll
                for (int t = 0; t < 4; ++t) {
                    float mu = S[t][r] * 0.05f;
                    float n2 = A[t][r][r] - 20.f * mu * mu;
                    st[(bi * 4 + r) * STSTR + t0loc + t] =
                        make_float2(mu, sqrtf(fmaxf(n2, 0.f)));
                }
        }
    }
    __syncthreads();

    // ---------------- Phase C2: correction + direct f32 store ----------------
    if (active) {
        float2 si[4][4], sj[4][4];                    // [row][t]
        #pragma unroll
        for (int r = 0; r < 4; ++r) {
            const float2* pi = &st[(bi * 4 + r) * STSTR + t0loc];
            const float2* pj = &st[(bj * 4 + r) * STSTR + t0loc];
            #pragma unroll
            for (int t = 0; t < 4; ++t) { si[r][t] = pi[t]; sj[r][t] = pj[t]; }
        }
        const int tg     = t0 + t0loc;                // even
        const int nvalid = T_TOT - tg;
        #pragma unroll
        for (int r = 0; r < 4; ++r) {
            int fi = bi * 4 + r;
            #pragma unroll
            for (int c = 0; c < 4; ++c) {
                int fj = bj * 4 + c;
                if (fj > fi) {
                    int p = fi * (63 - fi) / 2 + (fj - fi - 1);
                    float* po = ob + (size_t)p * T_TOT + tg;
                    float v[4];
                    #pragma unroll
                    for (int t = 0; t < 4; ++t) {
                        float num = A[t][r][c] - 20.f * si[r][t].x * sj[c][t].x;
                        float den = si[r][t].y * sj[c][t].y + 1e-8f;
                        v[t] = num * __builtin_amdgcn_rcpf(den);
                    }
                    if (nvalid >= 2) *(float2*)&po[0] = make_float2(v[0], v[1]);
                    if (nvalid >= 4) *(float2*)&po[2] = make_float2(v[2], v[3]);
                }
            }
        }
    }
}

extern "C" void kernel_launch(void* const* d_in, const int* in_sizes, int n_in,
                              void* d_out, int out_size, void* d_ws, size_t ws_size,
                              hipStream_t stream) {
    (void)in_sizes; (void)n_in; (void)out_size; (void)d_ws; (void)ws_size;
    const float* x = (const float*)d_in[0];
    float* out     = (float*)d_out;
    hipLaunchKernelGGL(tscorr_kernel, dim3(15, 256), dim3(TPB), 0, stream, x, out);
}